// Round 1
// baseline (257.020 us; speedup 1.0000x reference)
//
#include <hip/hip_runtime.h>

// ROI Align fp32, NCHW input (B=2, C=256, H=W=200), pooled 7x7, SAMPLE_NUM=2,
// SPATIAL_SCALE=0.25, ROI_END_MODE=1.
//
// Baseline design:
//  - one thread computes CPT=4 output channels for a single (n, ph, pw)
//  - thread linearization: s (=ph*7+pw) minor, then channel-group, then n,
//    so stores are wave-contiguous (out layout is n*C*49 + c*49 + s and the
//    4 channels are spaced CG=64 apart -> each k-store covers a contiguous run)
//  - bilinear geometry + 16 corner weights computed once per thread, reused
//    across the 4 channels
//  - validity mask folded into the per-axis weights (w=0 outside [-1,size])

constexpr int C_TOT  = 256;
constexpr int H_FEAT = 200;
constexpr int W_FEAT = 200;
constexpr int HW     = H_FEAT * W_FEAT;
constexpr int CPT    = 4;              // channels per thread
constexpr int CG     = C_TOT / CPT;    // 64 channel groups
constexpr int S_TOT  = 49;             // 7*7 pooled cells

__global__ __launch_bounds__(256) void roi_align_kernel(
    const float* __restrict__ feat,
    const float* __restrict__ rois,
    float* __restrict__ out,
    int N)
{
    int t = blockIdx.x * 256 + threadIdx.x;
    int total = N * CG * S_TOT;
    if (t >= total) return;

    int s   = t % S_TOT;
    int rem = t / S_TOT;
    int c0  = rem % CG;
    int n   = rem / CG;
    int ph  = s / 7;
    int pw  = s - ph * 7;

    const float* r = rois + (size_t)n * 5;
    int   b  = (int)r[0];
    float x1 = r[1] * 0.25f;
    float y1 = r[2] * 0.25f;
    float x2 = (r[3] + 1.0f) * 0.25f;
    float y2 = (r[4] + 1.0f) * 0.25f;
    float bin_w = fmaxf(x2 - x1, 1.0f) * (1.0f / 7.0f);
    float bin_h = fmaxf(y2 - y1, 1.0f) * (1.0f / 7.0f);

    int   roff[2][2], coff[2][2];
    float wy[2][2], wx[2][2];
    #pragma unroll
    for (int i = 0; i < 2; ++i) {
        // y axis sample g = 2*ph + i
        float gy  = (float)(2 * ph + i);
        float cy  = y1 + bin_h * ((gy + 0.5f) * 0.5f);
        bool  vy  = (cy >= -1.0f) && (cy <= (float)H_FEAT);
        float ccy = fminf(fmaxf(cy, 0.0f), (float)(H_FEAT - 1));
        int   ylo = (int)ccy;                 // ccy >= 0 -> trunc == floor
        int   yhi = min(ylo + 1, H_FEAT - 1);
        float fy  = ccy - (float)ylo;
        roff[i][0] = ylo * W_FEAT;
        roff[i][1] = yhi * W_FEAT;
        wy[i][0] = vy ? (1.0f - fy) : 0.0f;
        wy[i][1] = vy ? fy          : 0.0f;

        // x axis sample g = 2*pw + i
        float gx  = (float)(2 * pw + i);
        float cx  = x1 + bin_w * ((gx + 0.5f) * 0.5f);
        bool  vx  = (cx >= -1.0f) && (cx <= (float)W_FEAT);
        float ccx = fminf(fmaxf(cx, 0.0f), (float)(W_FEAT - 1));
        int   xlo = (int)ccx;
        int   xhi = min(xlo + 1, W_FEAT - 1);
        float fx  = ccx - (float)xlo;
        coff[i][0] = xlo;
        coff[i][1] = xhi;
        wx[i][0] = vx ? (1.0f - fx) : 0.0f;
        wx[i][1] = vx ? fx          : 0.0f;
    }

    // 16 corner weights + offsets, shared across the CPT channels
    float w16[16];
    int   o16[16];
    #pragma unroll
    for (int iy = 0; iy < 2; ++iy)
    #pragma unroll
    for (int ix = 0; ix < 2; ++ix)
    #pragma unroll
    for (int jy = 0; jy < 2; ++jy)
    #pragma unroll
    for (int jx = 0; jx < 2; ++jx) {
        int idx = ((iy * 2 + ix) * 2 + jy) * 2 + jx;
        w16[idx] = wy[iy][jy] * wx[ix][jx];
        o16[idx] = roff[iy][jy] + coff[ix][jx];
    }

    size_t base  = ((size_t)b * C_TOT + c0) * HW;
    size_t obase = (size_t)n * (C_TOT * S_TOT) + (size_t)c0 * S_TOT + s;

    #pragma unroll
    for (int k = 0; k < CPT; ++k) {
        const float* f = feat + base + (size_t)k * CG * HW;
        float acc = 0.0f;
        #pragma unroll
        for (int j = 0; j < 16; ++j)
            acc = fmaf(w16[j], f[o16[j]], acc);
        out[obase + (size_t)k * (CG * S_TOT)] = acc * 0.25f;
    }
}

extern "C" void kernel_launch(void* const* d_in, const int* in_sizes, int n_in,
                              void* d_out, int out_size, void* d_ws, size_t ws_size,
                              hipStream_t stream) {
    const float* feat = (const float*)d_in[0];
    const float* rois = (const float*)d_in[1];
    float* out = (float*)d_out;

    int N = in_sizes[1] / 5;
    int total  = N * CG * S_TOT;
    int blocks = (total + 255) / 256;
    roi_align_kernel<<<blocks, 256, 0, stream>>>(feat, rois, out, N);
}

// Round 2
// 103.796 us; speedup vs baseline: 2.4762x; 2.4762x over previous
//
#include <hip/hip_runtime.h>

// ROI Align fp32, NCHW input (B=2, C=256, H=W=200), pooled 7x7, SAMPLE_NUM=2,
// SPATIAL_SCALE=0.25, ROI_END_MODE=1.
//
// Round 2: two-phase pipeline.
//  Phase 1: NCHW -> NHWC transpose into d_ws (82 MB), tiled 32x32 via LDS,
//           both global read and write coalesced.
//  Phase 2: gather kernel. One wave per pooled cell (n, ph, pw); lane l holds
//           channels 4l..4l+3 as float4. Each of the 16 bilinear corners is a
//           single fully-coalesced 1 KB wave-load from the NHWC copy.
//           Results staged in LDS laid out exactly as the output ([c][s] flat),
//           then stored as linear float4 -> WRITE stays at the ideal 49 MB.
// Fallback: if ws_size < NHWC copy size, use the round-1 direct kernel.

constexpr int C_TOT  = 256;
constexpr int H_FEAT = 200;
constexpr int W_FEAT = 200;
constexpr int HW     = H_FEAT * W_FEAT;
constexpr int S_TOT  = 49;             // 7*7 pooled cells

// ---------------------------------------------------------------- transpose
// feat[b][c][s] -> featT[b][s][c], per-b 256 x 40000 matrix transpose.
__global__ __launch_bounds__(256) void nchw_to_nhwc_kernel(
    const float* __restrict__ feat,
    float* __restrict__ featT)
{
    __shared__ float tile[32][33];
    int tx = threadIdx.x;        // 0..31
    int ty = threadIdx.y;        // 0..7
    int s0 = blockIdx.x * 32;    // spatial tile base (1250 tiles)
    int c0 = blockIdx.y * 32;    // channel tile base (8 tiles)
    int b  = blockIdx.z;

    const float* src = feat + ((size_t)b * C_TOT) * HW;
    #pragma unroll
    for (int i = 0; i < 4; ++i) {
        int r = ty + i * 8;      // channel within tile
        tile[r][tx] = src[(size_t)(c0 + r) * HW + (s0 + tx)];
    }
    __syncthreads();
    float* dst = featT + ((size_t)b * HW) * C_TOT;
    #pragma unroll
    for (int i = 0; i < 4; ++i) {
        int r = ty + i * 8;      // spatial within tile
        dst[(size_t)(s0 + r) * C_TOT + (c0 + tx)] = tile[tx][r];
    }
}

// ---------------------------------------------------------------- gather
// One block per ROI. 4 waves; wave w handles cells s = w, w+4, ... (<49).
// Lane l accumulates channels 4l..4l+3 (float4).
__global__ __launch_bounds__(256) void roi_align_nhwc_kernel(
    const float* __restrict__ featT,
    const float* __restrict__ rois,
    float* __restrict__ out,
    int N)
{
    __shared__ alignas(16) float tile[C_TOT * S_TOT];   // [c][s] == output order

    int n    = blockIdx.x;
    int tid  = threadIdx.x;
    int wave = tid >> 6;
    int lane = tid & 63;

    const float* r = rois + (size_t)n * 5;
    int   b  = (int)r[0];
    float x1 = r[1] * 0.25f;
    float y1 = r[2] * 0.25f;
    float x2 = (r[3] + 1.0f) * 0.25f;
    float y2 = (r[4] + 1.0f) * 0.25f;
    float bin_w = fmaxf(x2 - x1, 1.0f) * (1.0f / 7.0f);
    float bin_h = fmaxf(y2 - y1, 1.0f) * (1.0f / 7.0f);

    const float* fbase = featT + (size_t)b * HW * C_TOT + (size_t)lane * 4;

    for (int s = wave; s < S_TOT; s += 4) {
        int ph = s / 7;
        int pw = s - ph * 7;

        int   yoff[2][2];
        int   xoff[2][2];
        float wy[2][2], wx[2][2];
        #pragma unroll
        for (int i = 0; i < 2; ++i) {
            float gy  = (float)(2 * ph + i);
            float cy  = y1 + bin_h * ((gy + 0.5f) * 0.5f);
            bool  vy  = (cy >= -1.0f) && (cy <= (float)H_FEAT);
            float ccy = fminf(fmaxf(cy, 0.0f), (float)(H_FEAT - 1));
            int   ylo = (int)ccy;
            int   yhi = min(ylo + 1, H_FEAT - 1);
            float fy  = ccy - (float)ylo;
            yoff[i][0] = ylo * W_FEAT;
            yoff[i][1] = yhi * W_FEAT;
            wy[i][0] = vy ? (1.0f - fy) : 0.0f;
            wy[i][1] = vy ? fy          : 0.0f;

            float gx  = (float)(2 * pw + i);
            float cx  = x1 + bin_w * ((gx + 0.5f) * 0.5f);
            bool  vx  = (cx >= -1.0f) && (cx <= (float)W_FEAT);
            float ccx = fminf(fmaxf(cx, 0.0f), (float)(W_FEAT - 1));
            int   xlo = (int)ccx;
            int   xhi = min(xlo + 1, W_FEAT - 1);
            float fx  = ccx - (float)xlo;
            xoff[i][0] = xlo;
            xoff[i][1] = xhi;
            wx[i][0] = vx ? (1.0f - fx) : 0.0f;
            wx[i][1] = vx ? fx          : 0.0f;
        }

        float4 acc = make_float4(0.f, 0.f, 0.f, 0.f);
        #pragma unroll
        for (int iy = 0; iy < 2; ++iy)
        #pragma unroll
        for (int jy = 0; jy < 2; ++jy)
        #pragma unroll
        for (int ix = 0; ix < 2; ++ix)
        #pragma unroll
        for (int jx = 0; jx < 2; ++jx) {
            float w = wy[iy][jy] * wx[ix][jx];
            const float4 v = *reinterpret_cast<const float4*>(
                fbase + (size_t)(yoff[iy][jy] + xoff[ix][jx]) * C_TOT);
            acc.x = fmaf(w, v.x, acc.x);
            acc.y = fmaf(w, v.y, acc.y);
            acc.z = fmaf(w, v.z, acc.z);
            acc.w = fmaf(w, v.w, acc.w);
        }
        acc.x *= 0.25f; acc.y *= 0.25f; acc.z *= 0.25f; acc.w *= 0.25f;

        int c = lane * 4;
        tile[(c + 0) * S_TOT + s] = acc.x;
        tile[(c + 1) * S_TOT + s] = acc.y;
        tile[(c + 2) * S_TOT + s] = acc.z;
        tile[(c + 3) * S_TOT + s] = acc.w;
    }
    __syncthreads();

    // Linear float4 store: tile flat layout == out[n] flat layout.
    const float4* t4 = reinterpret_cast<const float4*>(tile);
    float4* o4 = reinterpret_cast<float4*>(out + (size_t)n * (C_TOT * S_TOT));
    constexpr int Q = C_TOT * S_TOT / 4;   // 3136
    for (int q = tid; q < Q; q += 256)
        o4[q] = t4[q];
}

// ---------------------------------------------------------------- round-1 fallback
constexpr int CPT = 4;
constexpr int CG  = C_TOT / CPT;

__global__ __launch_bounds__(256) void roi_align_direct_kernel(
    const float* __restrict__ feat,
    const float* __restrict__ rois,
    float* __restrict__ out,
    int N)
{
    int t = blockIdx.x * 256 + threadIdx.x;
    int total = N * CG * S_TOT;
    if (t >= total) return;

    int s   = t % S_TOT;
    int rem = t / S_TOT;
    int c0  = rem % CG;
    int n   = rem / CG;
    int ph  = s / 7;
    int pw  = s - ph * 7;

    const float* r = rois + (size_t)n * 5;
    int   b  = (int)r[0];
    float x1 = r[1] * 0.25f;
    float y1 = r[2] * 0.25f;
    float x2 = (r[3] + 1.0f) * 0.25f;
    float y2 = (r[4] + 1.0f) * 0.25f;
    float bin_w = fmaxf(x2 - x1, 1.0f) * (1.0f / 7.0f);
    float bin_h = fmaxf(y2 - y1, 1.0f) * (1.0f / 7.0f);

    int   roff[2][2], coff[2][2];
    float wy[2][2], wx[2][2];
    #pragma unroll
    for (int i = 0; i < 2; ++i) {
        float gy  = (float)(2 * ph + i);
        float cy  = y1 + bin_h * ((gy + 0.5f) * 0.5f);
        bool  vy  = (cy >= -1.0f) && (cy <= (float)H_FEAT);
        float ccy = fminf(fmaxf(cy, 0.0f), (float)(H_FEAT - 1));
        int   ylo = (int)ccy;
        int   yhi = min(ylo + 1, H_FEAT - 1);
        float fy  = ccy - (float)ylo;
        roff[i][0] = ylo * W_FEAT;
        roff[i][1] = yhi * W_FEAT;
        wy[i][0] = vy ? (1.0f - fy) : 0.0f;
        wy[i][1] = vy ? fy          : 0.0f;

        float gx  = (float)(2 * pw + i);
        float cx  = x1 + bin_w * ((gx + 0.5f) * 0.5f);
        bool  vx  = (cx >= -1.0f) && (cx <= (float)W_FEAT);
        float ccx = fminf(fmaxf(cx, 0.0f), (float)(W_FEAT - 1));
        int   xlo = (int)ccx;
        int   xhi = min(xlo + 1, W_FEAT - 1);
        float fx  = ccx - (float)xlo;
        coff[i][0] = xlo;
        coff[i][1] = xhi;
        wx[i][0] = vx ? (1.0f - fx) : 0.0f;
        wx[i][1] = vx ? fx          : 0.0f;
    }

    float w16[16];
    int   o16[16];
    #pragma unroll
    for (int iy = 0; iy < 2; ++iy)
    #pragma unroll
    for (int ix = 0; ix < 2; ++ix)
    #pragma unroll
    for (int jy = 0; jy < 2; ++jy)
    #pragma unroll
    for (int jx = 0; jx < 2; ++jx) {
        int idx = ((iy * 2 + ix) * 2 + jy) * 2 + jx;
        w16[idx] = wy[iy][jy] * wx[ix][jx];
        o16[idx] = roff[iy][jy] + coff[ix][jx];
    }

    size_t base  = ((size_t)b * C_TOT + c0) * HW;
    size_t obase = (size_t)n * (C_TOT * S_TOT) + (size_t)c0 * S_TOT + s;

    #pragma unroll
    for (int k = 0; k < CPT; ++k) {
        const float* f = feat + base + (size_t)k * CG * HW;
        float acc = 0.0f;
        #pragma unroll
        for (int j = 0; j < 16; ++j)
            acc = fmaf(w16[j], f[o16[j]], acc);
        out[obase + (size_t)k * (CG * S_TOT)] = acc * 0.25f;
    }
}

extern "C" void kernel_launch(void* const* d_in, const int* in_sizes, int n_in,
                              void* d_out, int out_size, void* d_ws, size_t ws_size,
                              hipStream_t stream) {
    const float* feat = (const float*)d_in[0];
    const float* rois = (const float*)d_in[1];
    float* out = (float*)d_out;
    int N = in_sizes[1] / 5;

    size_t nhwc_bytes = (size_t)2 * HW * C_TOT * sizeof(float);   // 81.92 MB
    if (ws_size >= nhwc_bytes) {
        float* featT = (float*)d_ws;
        dim3 tgrid(HW / 32, C_TOT / 32, 2);
        dim3 tblk(32, 8);
        nchw_to_nhwc_kernel<<<tgrid, tblk, 0, stream>>>(feat, featT);
        roi_align_nhwc_kernel<<<N, 256, 0, stream>>>(featT, rois, out, N);
    } else {
        int total  = N * CG * S_TOT;
        int blocks = (total + 255) / 256;
        roi_align_direct_kernel<<<blocks, 256, 0, stream>>>(feat, rois, out, N);
    }
}

// Round 3
// 100.904 us; speedup vs baseline: 2.5472x; 1.0287x over previous
//
#include <hip/hip_runtime.h>

// ROI Align fp32, NCHW input (B=2, C=256, H=W=200), pooled 7x7, SAMPLE_NUM=2,
// SPATIAL_SCALE=0.25, ROI_END_MODE=1.
//
// Round 3: same two-phase pipeline as round 2, but the gather kernel uses
// 512 threads (8 waves) per ROI-block. LDS stays 50 KB -> still 3 blocks/CU,
// but now 24 waves/CU (vs 12) for latency hiding, and per-block work halves.
//  Phase 1: NCHW -> NHWC transpose into d_ws (82 MB), ~6.5 TB/s (at ceiling).
//  Phase 2: gather. Wave w handles cells s = w, w+8, ...; lane l holds
//           channels 4l..4l+3 as float4; each bilinear corner is one
//           coalesced 1 KB wave-load. Output staged in LDS in exact output
//           order, stored as linear float4.

constexpr int C_TOT  = 256;
constexpr int H_FEAT = 200;
constexpr int W_FEAT = 200;
constexpr int HW     = H_FEAT * W_FEAT;
constexpr int S_TOT  = 49;             // 7*7 pooled cells

// ---------------------------------------------------------------- transpose
__global__ __launch_bounds__(256) void nchw_to_nhwc_kernel(
    const float* __restrict__ feat,
    float* __restrict__ featT)
{
    __shared__ float tile[32][33];
    int tx = threadIdx.x;        // 0..31
    int ty = threadIdx.y;        // 0..7
    int s0 = blockIdx.x * 32;
    int c0 = blockIdx.y * 32;
    int b  = blockIdx.z;

    const float* src = feat + ((size_t)b * C_TOT) * HW;
    #pragma unroll
    for (int i = 0; i < 4; ++i) {
        int r = ty + i * 8;
        tile[r][tx] = src[(size_t)(c0 + r) * HW + (s0 + tx)];
    }
    __syncthreads();
    float* dst = featT + ((size_t)b * HW) * C_TOT;
    #pragma unroll
    for (int i = 0; i < 4; ++i) {
        int r = ty + i * 8;
        dst[(size_t)(s0 + r) * C_TOT + (c0 + tx)] = tile[tx][r];
    }
}

// ---------------------------------------------------------------- gather
__global__ __launch_bounds__(512) void roi_align_nhwc_kernel(
    const float* __restrict__ featT,
    const float* __restrict__ rois,
    float* __restrict__ out,
    int N)
{
    __shared__ alignas(16) float tile[C_TOT * S_TOT];   // [c][s] == output order

    int n    = blockIdx.x;
    int tid  = threadIdx.x;
    int wave = tid >> 6;         // 0..7
    int lane = tid & 63;

    const float* r = rois + (size_t)n * 5;
    int   b  = (int)r[0];
    float x1 = r[1] * 0.25f;
    float y1 = r[2] * 0.25f;
    float x2 = (r[3] + 1.0f) * 0.25f;
    float y2 = (r[4] + 1.0f) * 0.25f;
    float bin_w = fmaxf(x2 - x1, 1.0f) * (1.0f / 7.0f);
    float bin_h = fmaxf(y2 - y1, 1.0f) * (1.0f / 7.0f);

    const float* fbase = featT + (size_t)b * HW * C_TOT + (size_t)lane * 4;

    for (int s = wave; s < S_TOT; s += 8) {
        int ph = s / 7;
        int pw = s - ph * 7;

        int   yoff[2][2];
        int   xoff[2][2];
        float wy[2][2], wx[2][2];
        #pragma unroll
        for (int i = 0; i < 2; ++i) {
            float gy  = (float)(2 * ph + i);
            float cy  = y1 + bin_h * ((gy + 0.5f) * 0.5f);
            bool  vy  = (cy >= -1.0f) && (cy <= (float)H_FEAT);
            float ccy = fminf(fmaxf(cy, 0.0f), (float)(H_FEAT - 1));
            int   ylo = (int)ccy;
            int   yhi = min(ylo + 1, H_FEAT - 1);
            float fy  = ccy - (float)ylo;
            yoff[i][0] = ylo * W_FEAT;
            yoff[i][1] = yhi * W_FEAT;
            wy[i][0] = vy ? (1.0f - fy) : 0.0f;
            wy[i][1] = vy ? fy          : 0.0f;

            float gx  = (float)(2 * pw + i);
            float cx  = x1 + bin_w * ((gx + 0.5f) * 0.5f);
            bool  vx  = (cx >= -1.0f) && (cx <= (float)W_FEAT);
            float ccx = fminf(fmaxf(cx, 0.0f), (float)(W_FEAT - 1));
            int   xlo = (int)ccx;
            int   xhi = min(xlo + 1, W_FEAT - 1);
            float fx  = ccx - (float)xlo;
            xoff[i][0] = xlo;
            xoff[i][1] = xhi;
            wx[i][0] = vx ? (1.0f - fx) : 0.0f;
            wx[i][1] = vx ? fx          : 0.0f;
        }

        float4 acc = make_float4(0.f, 0.f, 0.f, 0.f);
        #pragma unroll
        for (int iy = 0; iy < 2; ++iy)
        #pragma unroll
        for (int jy = 0; jy < 2; ++jy)
        #pragma unroll
        for (int ix = 0; ix < 2; ++ix)
        #pragma unroll
        for (int jx = 0; jx < 2; ++jx) {
            float w = wy[iy][jy] * wx[ix][jx];
            const float4 v = *reinterpret_cast<const float4*>(
                fbase + (size_t)(yoff[iy][jy] + xoff[ix][jx]) * C_TOT);
            acc.x = fmaf(w, v.x, acc.x);
            acc.y = fmaf(w, v.y, acc.y);
            acc.z = fmaf(w, v.z, acc.z);
            acc.w = fmaf(w, v.w, acc.w);
        }
        acc.x *= 0.25f; acc.y *= 0.25f; acc.z *= 0.25f; acc.w *= 0.25f;

        int c = lane * 4;
        tile[(c + 0) * S_TOT + s] = acc.x;
        tile[(c + 1) * S_TOT + s] = acc.y;
        tile[(c + 2) * S_TOT + s] = acc.z;
        tile[(c + 3) * S_TOT + s] = acc.w;
    }
    __syncthreads();

    // Linear float4 store: tile flat layout == out[n] flat layout.
    const float4* t4 = reinterpret_cast<const float4*>(tile);
    float4* o4 = reinterpret_cast<float4*>(out + (size_t)n * (C_TOT * S_TOT));
    constexpr int Q = C_TOT * S_TOT / 4;   // 3136
    for (int q = tid; q < Q; q += 512)
        o4[q] = t4[q];
}

// ---------------------------------------------------------------- round-1 fallback
constexpr int CPT = 4;
constexpr int CG  = C_TOT / CPT;

__global__ __launch_bounds__(256) void roi_align_direct_kernel(
    const float* __restrict__ feat,
    const float* __restrict__ rois,
    float* __restrict__ out,
    int N)
{
    int t = blockIdx.x * 256 + threadIdx.x;
    int total = N * CG * S_TOT;
    if (t >= total) return;

    int s   = t % S_TOT;
    int rem = t / S_TOT;
    int c0  = rem % CG;
    int n   = rem / CG;
    int ph  = s / 7;
    int pw  = s - ph * 7;

    const float* r = rois + (size_t)n * 5;
    int   b  = (int)r[0];
    float x1 = r[1] * 0.25f;
    float y1 = r[2] * 0.25f;
    float x2 = (r[3] + 1.0f) * 0.25f;
    float y2 = (r[4] + 1.0f) * 0.25f;
    float bin_w = fmaxf(x2 - x1, 1.0f) * (1.0f / 7.0f);
    float bin_h = fmaxf(y2 - y1, 1.0f) * (1.0f / 7.0f);

    int   roff[2][2], coff[2][2];
    float wy[2][2], wx[2][2];
    #pragma unroll
    for (int i = 0; i < 2; ++i) {
        float gy  = (float)(2 * ph + i);
        float cy  = y1 + bin_h * ((gy + 0.5f) * 0.5f);
        bool  vy  = (cy >= -1.0f) && (cy <= (float)H_FEAT);
        float ccy = fminf(fmaxf(cy, 0.0f), (float)(H_FEAT - 1));
        int   ylo = (int)ccy;
        int   yhi = min(ylo + 1, H_FEAT - 1);
        float fy  = ccy - (float)ylo;
        roff[i][0] = ylo * W_FEAT;
        roff[i][1] = yhi * W_FEAT;
        wy[i][0] = vy ? (1.0f - fy) : 0.0f;
        wy[i][1] = vy ? fy          : 0.0f;

        float gx  = (float)(2 * pw + i);
        float cx  = x1 + bin_w * ((gx + 0.5f) * 0.5f);
        bool  vx  = (cx >= -1.0f) && (cx <= (float)W_FEAT);
        float ccx = fminf(fmaxf(cx, 0.0f), (float)(W_FEAT - 1));
        int   xlo = (int)ccx;
        int   xhi = min(xlo + 1, W_FEAT - 1);
        float fx  = ccx - (float)xlo;
        coff[i][0] = xlo;
        coff[i][1] = xhi;
        wx[i][0] = vx ? (1.0f - fx) : 0.0f;
        wx[i][1] = vx ? fx          : 0.0f;
    }

    float w16[16];
    int   o16[16];
    #pragma unroll
    for (int iy = 0; iy < 2; ++iy)
    #pragma unroll
    for (int ix = 0; ix < 2; ++ix)
    #pragma unroll
    for (int jy = 0; jy < 2; ++jy)
    #pragma unroll
    for (int jx = 0; jx < 2; ++jx) {
        int idx = ((iy * 2 + ix) * 2 + jy) * 2 + jx;
        w16[idx] = wy[iy][jy] * wx[ix][jx];
        o16[idx] = roff[iy][jy] + coff[ix][jx];
    }

    size_t base  = ((size_t)b * C_TOT + c0) * HW;
    size_t obase = (size_t)n * (C_TOT * S_TOT) + (size_t)c0 * S_TOT + s;

    #pragma unroll
    for (int k = 0; k < CPT; ++k) {
        const float* f = feat + base + (size_t)k * CG * HW;
        float acc = 0.0f;
        #pragma unroll
        for (int j = 0; j < 16; ++j)
            acc = fmaf(w16[j], f[o16[j]], acc);
        out[obase + (size_t)k * (CG * S_TOT)] = acc * 0.25f;
    }
}

extern "C" void kernel_launch(void* const* d_in, const int* in_sizes, int n_in,
                              void* d_out, int out_size, void* d_ws, size_t ws_size,
                              hipStream_t stream) {
    const float* feat = (const float*)d_in[0];
    const float* rois = (const float*)d_in[1];
    float* out = (float*)d_out;
    int N = in_sizes[1] / 5;

    size_t nhwc_bytes = (size_t)2 * HW * C_TOT * sizeof(float);   // 81.92 MB
    if (ws_size >= nhwc_bytes) {
        float* featT = (float*)d_ws;
        dim3 tgrid(HW / 32, C_TOT / 32, 2);
        dim3 tblk(32, 8);
        nchw_to_nhwc_kernel<<<tgrid, tblk, 0, stream>>>(feat, featT);
        roi_align_nhwc_kernel<<<N, 512, 0, stream>>>(featT, rois, out, N);
    } else {
        int total  = N * CG * S_TOT;
        int blocks = (total + 255) / 256;
        roi_align_direct_kernel<<<blocks, 256, 0, stream>>>(feat, rois, out, N);
    }
}

// Round 4
// 63.042 us; speedup vs baseline: 4.0770x; 1.6006x over previous
//
#include <hip/hip_runtime.h>
#include <hip/hip_bf16.h>

// ROI Align fp32, NCHW input (B=2, C=256, H=W=200), pooled 7x7, SAMPLE_NUM=2,
// SPATIAL_SCALE=0.25, ROI_END_MODE=1.
//
// Round 4: the gather is cache-read-BW bound (784 MB requested @ ~10.4 TB/s).
// Halve the gathered bytes: NHWC staging copy is bf16 (fp32 accumulate).
//  Phase 1: NCHW fp32 -> NHWC bf16 transpose into d_ws (41 MB, L3-resident).
//  Phase 2: gather. One block (512 thr, 8 waves) per ROI; wave handles cells
//           s = w, w+8, ...; lane l holds channels 4l..4l+3 (ushort4 = 8 B);
//           each bilinear corner is one coalesced 512 B wave-load. Results
//           accumulated fp32, staged in LDS in exact output order, stored as
//           linear float4 (WRITE stays at the ideal 49 MB).
// Fallback: direct fp32 kernel if ws too small.

constexpr int C_TOT  = 256;
constexpr int H_FEAT = 200;
constexpr int W_FEAT = 200;
constexpr int HW     = H_FEAT * W_FEAT;
constexpr int S_TOT  = 49;             // 7*7 pooled cells

// ---------------------------------------------------------------- transpose
// feat[b][c][s] (fp32) -> featT[b][s][c] (bf16, RNE).
__global__ __launch_bounds__(256) void nchw_to_nhwc_bf16_kernel(
    const float* __restrict__ feat,
    unsigned short* __restrict__ featT)
{
    __shared__ float tile[32][33];
    int tx = threadIdx.x;        // 0..31
    int ty = threadIdx.y;        // 0..7
    int s0 = blockIdx.x * 32;
    int c0 = blockIdx.y * 32;
    int b  = blockIdx.z;

    const float* src = feat + ((size_t)b * C_TOT) * HW;
    #pragma unroll
    for (int i = 0; i < 4; ++i) {
        int r = ty + i * 8;      // channel within tile
        tile[r][tx] = src[(size_t)(c0 + r) * HW + (s0 + tx)];
    }
    __syncthreads();
    unsigned short* dst = featT + ((size_t)b * HW) * C_TOT;
    #pragma unroll
    for (int i = 0; i < 4; ++i) {
        int r = ty + i * 8;      // spatial within tile
        float x = tile[tx][r];
        unsigned int u = __float_as_uint(x);
        unsigned int rb = (u + 0x7fffu + ((u >> 16) & 1u)) >> 16;   // RNE
        dst[(size_t)(s0 + r) * C_TOT + (c0 + tx)] = (unsigned short)rb;
    }
}

// ---------------------------------------------------------------- gather
__global__ __launch_bounds__(512) void roi_align_nhwc_kernel(
    const unsigned short* __restrict__ featT,
    const float* __restrict__ rois,
    float* __restrict__ out,
    int N)
{
    __shared__ alignas(16) float tile[C_TOT * S_TOT];   // [c][s] == output order

    int n    = blockIdx.x;
    int tid  = threadIdx.x;
    int wave = tid >> 6;         // 0..7
    int lane = tid & 63;

    const float* r = rois + (size_t)n * 5;
    int   b  = (int)r[0];
    float x1 = r[1] * 0.25f;
    float y1 = r[2] * 0.25f;
    float x2 = (r[3] + 1.0f) * 0.25f;
    float y2 = (r[4] + 1.0f) * 0.25f;
    float bin_w = fmaxf(x2 - x1, 1.0f) * (1.0f / 7.0f);
    float bin_h = fmaxf(y2 - y1, 1.0f) * (1.0f / 7.0f);

    const unsigned short* fbase =
        featT + (size_t)b * HW * C_TOT + (size_t)lane * 4;

    for (int s = wave; s < S_TOT; s += 8) {
        int ph = s / 7;
        int pw = s - ph * 7;

        int   yoff[2][2];
        int   xoff[2][2];
        float wy[2][2], wx[2][2];
        #pragma unroll
        for (int i = 0; i < 2; ++i) {
            float gy  = (float)(2 * ph + i);
            float cy  = y1 + bin_h * ((gy + 0.5f) * 0.5f);
            bool  vy  = (cy >= -1.0f) && (cy <= (float)H_FEAT);
            float ccy = fminf(fmaxf(cy, 0.0f), (float)(H_FEAT - 1));
            int   ylo = (int)ccy;
            int   yhi = min(ylo + 1, H_FEAT - 1);
            float fy  = ccy - (float)ylo;
            yoff[i][0] = ylo * W_FEAT;
            yoff[i][1] = yhi * W_FEAT;
            wy[i][0] = vy ? (1.0f - fy) : 0.0f;
            wy[i][1] = vy ? fy          : 0.0f;

            float gx  = (float)(2 * pw + i);
            float cx  = x1 + bin_w * ((gx + 0.5f) * 0.5f);
            bool  vx  = (cx >= -1.0f) && (cx <= (float)W_FEAT);
            float ccx = fminf(fmaxf(cx, 0.0f), (float)(W_FEAT - 1));
            int   xlo = (int)ccx;
            int   xhi = min(xlo + 1, W_FEAT - 1);
            float fx  = ccx - (float)xlo;
            xoff[i][0] = xlo;
            xoff[i][1] = xhi;
            wx[i][0] = vx ? (1.0f - fx) : 0.0f;
            wx[i][1] = vx ? fx          : 0.0f;
        }

        float4 acc = make_float4(0.f, 0.f, 0.f, 0.f);
        #pragma unroll
        for (int iy = 0; iy < 2; ++iy)
        #pragma unroll
        for (int jy = 0; jy < 2; ++jy)
        #pragma unroll
        for (int ix = 0; ix < 2; ++ix)
        #pragma unroll
        for (int jx = 0; jx < 2; ++jx) {
            float w = wy[iy][jy] * wx[ix][jx];
            const ushort4 v = *reinterpret_cast<const ushort4*>(
                fbase + (size_t)(yoff[iy][jy] + xoff[ix][jx]) * C_TOT);
            float f0 = __uint_as_float((unsigned int)v.x << 16);
            float f1 = __uint_as_float((unsigned int)v.y << 16);
            float f2 = __uint_as_float((unsigned int)v.z << 16);
            float f3 = __uint_as_float((unsigned int)v.w << 16);
            acc.x = fmaf(w, f0, acc.x);
            acc.y = fmaf(w, f1, acc.y);
            acc.z = fmaf(w, f2, acc.z);
            acc.w = fmaf(w, f3, acc.w);
        }
        acc.x *= 0.25f; acc.y *= 0.25f; acc.z *= 0.25f; acc.w *= 0.25f;

        int c = lane * 4;
        tile[(c + 0) * S_TOT + s] = acc.x;
        tile[(c + 1) * S_TOT + s] = acc.y;
        tile[(c + 2) * S_TOT + s] = acc.z;
        tile[(c + 3) * S_TOT + s] = acc.w;
    }
    __syncthreads();

    // Linear float4 store: tile flat layout == out[n] flat layout.
    const float4* t4 = reinterpret_cast<const float4*>(tile);
    float4* o4 = reinterpret_cast<float4*>(out + (size_t)n * (C_TOT * S_TOT));
    constexpr int Q = C_TOT * S_TOT / 4;   // 3136
    for (int q = tid; q < Q; q += 512)
        o4[q] = t4[q];
}

// ---------------------------------------------------------------- fp32 fallback
constexpr int CPT = 4;
constexpr int CG  = C_TOT / CPT;

__global__ __launch_bounds__(256) void roi_align_direct_kernel(
    const float* __restrict__ feat,
    const float* __restrict__ rois,
    float* __restrict__ out,
    int N)
{
    int t = blockIdx.x * 256 + threadIdx.x;
    int total = N * CG * S_TOT;
    if (t >= total) return;

    int s   = t % S_TOT;
    int rem = t / S_TOT;
    int c0  = rem % CG;
    int n   = rem / CG;
    int ph  = s / 7;
    int pw  = s - ph * 7;

    const float* r = rois + (size_t)n * 5;
    int   b  = (int)r[0];
    float x1 = r[1] * 0.25f;
    float y1 = r[2] * 0.25f;
    float x2 = (r[3] + 1.0f) * 0.25f;
    float y2 = (r[4] + 1.0f) * 0.25f;
    float bin_w = fmaxf(x2 - x1, 1.0f) * (1.0f / 7.0f);
    float bin_h = fmaxf(y2 - y1, 1.0f) * (1.0f / 7.0f);

    int   roff[2][2], coff[2][2];
    float wy[2][2], wx[2][2];
    #pragma unroll
    for (int i = 0; i < 2; ++i) {
        float gy  = (float)(2 * ph + i);
        float cy  = y1 + bin_h * ((gy + 0.5f) * 0.5f);
        bool  vy  = (cy >= -1.0f) && (cy <= (float)H_FEAT);
        float ccy = fminf(fmaxf(cy, 0.0f), (float)(H_FEAT - 1));
        int   ylo = (int)ccy;
        int   yhi = min(ylo + 1, H_FEAT - 1);
        float fy  = ccy - (float)ylo;
        roff[i][0] = ylo * W_FEAT;
        roff[i][1] = yhi * W_FEAT;
        wy[i][0] = vy ? (1.0f - fy) : 0.0f;
        wy[i][1] = vy ? fy          : 0.0f;

        float gx  = (float)(2 * pw + i);
        float cx  = x1 + bin_w * ((gx + 0.5f) * 0.5f);
        bool  vx  = (cx >= -1.0f) && (cx <= (float)W_FEAT);
        float ccx = fminf(fmaxf(cx, 0.0f), (float)(W_FEAT - 1));
        int   xlo = (int)ccx;
        int   xhi = min(xlo + 1, W_FEAT - 1);
        float fx  = ccx - (float)xlo;
        coff[i][0] = xlo;
        coff[i][1] = xhi;
        wx[i][0] = vx ? (1.0f - fx) : 0.0f;
        wx[i][1] = vx ? fx          : 0.0f;
    }

    float w16[16];
    int   o16[16];
    #pragma unroll
    for (int iy = 0; iy < 2; ++iy)
    #pragma unroll
    for (int ix = 0; ix < 2; ++ix)
    #pragma unroll
    for (int jy = 0; jy < 2; ++jy)
    #pragma unroll
    for (int jx = 0; jx < 2; ++jx) {
        int idx = ((iy * 2 + ix) * 2 + jy) * 2 + jx;
        w16[idx] = wy[iy][jy] * wx[ix][jx];
        o16[idx] = roff[iy][jy] + coff[ix][jx];
    }

    size_t base  = ((size_t)b * C_TOT + c0) * HW;
    size_t obase = (size_t)n * (C_TOT * S_TOT) + (size_t)c0 * S_TOT + s;

    #pragma unroll
    for (int k = 0; k < CPT; ++k) {
        const float* f = feat + base + (size_t)k * CG * HW;
        float acc = 0.0f;
        #pragma unroll
        for (int j = 0; j < 16; ++j)
            acc = fmaf(w16[j], f[o16[j]], acc);
        out[obase + (size_t)k * (CG * S_TOT)] = acc * 0.25f;
    }
}

extern "C" void kernel_launch(void* const* d_in, const int* in_sizes, int n_in,
                              void* d_out, int out_size, void* d_ws, size_t ws_size,
                              hipStream_t stream) {
    const float* feat = (const float*)d_in[0];
    const float* rois = (const float*)d_in[1];
    float* out = (float*)d_out;
    int N = in_sizes[1] / 5;

    size_t nhwc_bytes = (size_t)2 * HW * C_TOT * sizeof(unsigned short); // 41 MB
    if (ws_size >= nhwc_bytes) {
        unsigned short* featT = (unsigned short*)d_ws;
        dim3 tgrid(HW / 32, C_TOT / 32, 2);
        dim3 tblk(32, 8);
        nchw_to_nhwc_bf16_kernel<<<tgrid, tblk, 0, stream>>>(feat, featT);
        roi_align_nhwc_kernel<<<N, 512, 0, stream>>>(featT, rois, out, N);
    } else {
        int total  = N * CG * S_TOT;
        int blocks = (total + 255) / 256;
        roi_align_direct_kernel<<<blocks, 256, 0, stream>>>(feat, rois, out, N);
    }
}